// Round 1
// baseline (142.443 us; speedup 1.0000x reference)
//
#include <hip/hip_runtime.h>
#include <stdint.h>

typedef unsigned int u32;
typedef unsigned long long u64;
typedef unsigned short u16;
typedef unsigned char u8;

#define NPTS 8192
#define NTILES (32 * 33)

// neighbor-list geometry for the group-sequential resolver
#define EXTR 16          // row-major ext slots per point (reg-prefetched)
#define INGR 2           // in-group (same 128-rank block) slots per point
#define OVFC 16          // shared overflow slots per point (exactness tail)
#define GR (NPTS / 128)  // 64 groups of 128 ranks

// ---------------------------------------------------------------------------
// A: rank by counting, register-tiled 4 points/thread (unchanged core).
// Block 0 zeroes cnt_ext | cnt_ing | cnt_ovf (3*NPTS u32).
// ---------------------------------------------------------------------------
__global__ __launch_bounds__(1024) void k_rank(const float* __restrict__ coords,
                                               const float* __restrict__ scores,
                                               u32* __restrict__ sorted_id,
                                               float* __restrict__ sx,
                                               float* __restrict__ sy,
                                               float* __restrict__ ss,
                                               u32* __restrict__ zero_region) {
  __shared__ u32 skey[NPTS];
  __shared__ u32 part[16][4];
  int t = threadIdx.x, B = blockIdx.x;
  for (int k = t; k < NPTS; k += 1024) skey[k] = __float_as_uint(scores[k]);
  if (B == 0) {
    for (int k = t; k < 3 * NPTS; k += 1024) zero_region[k] = 0;
  }
  __syncthreads();

  int qd = t >> 7;        // quad 0..7 (4 points each)
  int s = t & 127;        // slice 0..127 (64 keys each)
  int p0 = B * 32 + qd * 4;
  int sp = B >> 1;        // the one slice containing this block's points
  u32 kp0 = skey[p0], kp1 = skey[p0 + 1], kp2 = skey[p0 + 2], kp3 = skey[p0 + 3];
  u32 c0 = 0, c1 = 0, c2 = 0, c3 = 0;
  const uint4* k4 = (const uint4*)skey;

  if (s != sp) {
    bool below = (s < sp);
    u32 a0 = below ? kp0 - 1u : kp0;  // >= via > (kp-1); kp==0 fixed below
    u32 a1 = below ? kp1 - 1u : kp1;
    u32 a2 = below ? kp2 - 1u : kp2;
    u32 a3 = below ? kp3 - 1u : kp3;
    int b4 = s << 4;
#pragma unroll 4
    for (int j = 0; j < 16; ++j) {
      int jj = (j + s) & 15;          // rotate across bank groups
      uint4 kv = k4[b4 + jj];
      c0 += (kv.x > a0) + (kv.y > a0) + (kv.z > a0) + (kv.w > a0);
      c1 += (kv.x > a1) + (kv.y > a1) + (kv.z > a1) + (kv.w > a1);
      c2 += (kv.x > a2) + (kv.y > a2) + (kv.z > a2) + (kv.w > a2);
      c3 += (kv.x > a3) + (kv.y > a3) + (kv.z > a3) + (kv.w > a3);
    }
    if (below) {  // underflow fixup: kp==0 means all 64 keys count as >=
      if (kp0 == 0) c0 += 64;
      if (kp1 == 0) c1 += 64;
      if (kp2 == 0) c2 += 64;
      if (kp3 == 0) c3 += 64;
    }
  } else {
    int q0 = s << 6;
    int mo = p0 - q0;  // 0..60, multiple of 4
    u32 a0 = kp0 - 1u, a1 = kp1 - 1u, a2 = kp2 - 1u, a3 = kp3 - 1u;
    for (int j = 0; j < mo; ++j) {       // q < p0: count >=
      u32 kq = skey[q0 + j];
      c0 += (kq > a0); c1 += (kq > a1); c2 += (kq > a2); c3 += (kq > a3);
    }
    if (kp0 == 0) c0 += mo;
    if (kp1 == 0) c1 += mo;
    if (kp2 == 0) c2 += mo;
    if (kp3 == 0) c3 += mo;
#pragma unroll
    for (int j2 = 0; j2 < 4; ++j2) {     // q in [p0, p0+4): exact tie logic
      int q = p0 + j2;
      u32 kq = skey[q];
      c0 += (kq > kp0) || (kq == kp0 && q < p0);
      c1 += (kq > kp1) || (kq == kp1 && q < p0 + 1);
      c2 += (kq > kp2) || (kq == kp2 && q < p0 + 2);
      c3 += (kq > kp3) || (kq == kp3 && q < p0 + 3);
    }
    for (int j = mo + 4; j < 64; ++j) {  // q > p_e: count >
      u32 kq = skey[q0 + j];
      c0 += (kq > kp0); c1 += (kq > kp1); c2 += (kq > kp2); c3 += (kq > kp3);
    }
  }

#pragma unroll
  for (int d = 1; d < 64; d <<= 1) {
    c0 += __shfl_xor(c0, d);
    c1 += __shfl_xor(c1, d);
    c2 += __shfl_xor(c2, d);
    c3 += __shfl_xor(c3, d);
  }
  int w = t >> 6;
  if ((t & 63) == 0) { part[w][0] = c0; part[w][1] = c1; part[w][2] = c2; part[w][3] = c3; }
  __syncthreads();
  if (t < 32) {
    int qd2 = t >> 2, e = t & 3;
    u32 r = part[qd2 * 2][e] + part[qd2 * 2 + 1][e];
    int p = B * 32 + t;
    sorted_id[r] = (u32)p;
    sx[r] = coords[2 * p];      // bitwise copies keep arithmetic exact
    sy[r] = coords[2 * p + 1];
    ss[r] = scores[p];
  }
}

// ---------------------------------------------------------------------------
// B: neighbor lists (triangular-tile lineage), split at insert time into
// ext (different 128-rank group, row-major 16 slots), ing (same 128-group,
// 2 slots) and a shared overflow list (exactness tail, ~0-2 entries total).
// d2<64 <=> sqrt(d2)<8 exactly in f32. Distance arithmetic unchanged.
// ---------------------------------------------------------------------------
__global__ __launch_bounds__(256) void k_nbr(const float* __restrict__ sx,
                                             const float* __restrict__ sy,
                                             u32* __restrict__ cnt_ext,
                                             u32* __restrict__ cnt_ing,
                                             u32* __restrict__ cnt_ovf,
                                             u16* __restrict__ nbr_ext,
                                             u16* __restrict__ nbr_ing,
                                             u16* __restrict__ nbr_ovf) {
  __shared__ float qx[128], qy[128];
  int b = blockIdx.x;
  int R = (int)((__fsqrt_rn(4.0f * (float)b + 1.0f) - 1.0f) * 0.5f);
  while ((R + 1) * (R + 2) <= b) ++R;
  while (R * (R + 1) > b) --R;
  int C = b - R * (R + 1);
  int t = threadIdx.x;
  int q0 = C << 7;
  int r = (R << 8) + t;
  if (t < 128) qx[t] = sx[q0 + t];
  else         qy[t - 128] = sy[q0 + t - 128];
  __syncthreads();

  float x = sx[r], y = sy[r];
  int jlim = 128;
  int dC = C - 2 * R;
  if (dC >= 0) {
    jlim = t - (dC << 7);
    if (jlim < 0) jlim = 0;
    if (jlim > 128) jlim = 128;
  }
  const float4* x4 = (const float4*)qx;
  const float4* y4 = (const float4*)qy;
  int rgrp = r >> 7;
  for (int jg = 0; jg < 4; ++jg) {
    int base = jg << 5;
    int v = jlim - base;
    u32 gm = (v >= 32) ? 0xFFFFFFFFu : ((v <= 0) ? 0u : ((1u << v) - 1u));
    u32 m = 0;
#pragma unroll
    for (int j4 = 0; j4 < 8; ++j4) {
      float4 xv = x4[(base >> 2) + j4];
      float4 yv = y4[(base >> 2) + j4];
      // mirror reference arithmetic: sub, mul, mul, add (no fma contraction)
      float dx0 = __fsub_rn(x, xv.x), dy0 = __fsub_rn(y, yv.x);
      float dx1 = __fsub_rn(x, xv.y), dy1 = __fsub_rn(y, yv.y);
      float dx2 = __fsub_rn(x, xv.z), dy2 = __fsub_rn(y, yv.z);
      float dx3 = __fsub_rn(x, xv.w), dy3 = __fsub_rn(y, yv.w);
      if (__fadd_rn(__fmul_rn(dx0, dx0), __fmul_rn(dy0, dy0)) < 64.0f) m |= 1u << (4 * j4 + 0);
      if (__fadd_rn(__fmul_rn(dx1, dx1), __fmul_rn(dy1, dy1)) < 64.0f) m |= 1u << (4 * j4 + 1);
      if (__fadd_rn(__fmul_rn(dx2, dx2), __fmul_rn(dy2, dy2)) < 64.0f) m |= 1u << (4 * j4 + 2);
      if (__fadd_rn(__fmul_rn(dx3, dx3), __fmul_rn(dy3, dy3)) < 64.0f) m |= 1u << (4 * j4 + 3);
    }
    m &= gm;
    while (m) {  // rare: lambda ~3 hits/point total
      int j2 = __builtin_ctz(m);
      m &= m - 1;
      int q = q0 + base + j2;   // strictly q < r (lower triangle)
      if ((q >> 7) == rgrp) {
        u32 sl = atomicAdd(&cnt_ing[r], 1u);
        if (sl < INGR) nbr_ing[2 * r + sl] = (u16)q;
        else { u32 so = atomicAdd(&cnt_ovf[r], 1u); if (so < OVFC) nbr_ovf[so * NPTS + r] = (u16)q; }
      } else {
        u32 sl = atomicAdd(&cnt_ext[r], 1u);
        if (sl < EXTR) nbr_ext[EXTR * r + sl] = (u16)q;
        else { u32 so = atomicAdd(&cnt_ovf[r], 1u); if (so < OVFC) nbr_ovf[so * NPTS + r] = (u16)q; }
      }
    }
  }
}

// ---------------------------------------------------------------------------
// C: single-wave group-sequential exact greedy resolver. 64 groups x 128
// ranks; cross-group deps are final (plain LDS byte reads, no rounds);
// in-group deps resolved by a bounded ballot fixpoint over a 64-bit live
// mask (deps only point to earlier lanes -> unique fixpoint = exact greedy,
// <=64 iterations, typically 1-3). Neighbor lists register-prefetched two
// resolves ahead to hide L3 latency. One near-free 1-wave barrier per group.
// ---------------------------------------------------------------------------
#define ZS NPTS  // LDS zero slot for predicated-off ext reads

#define DECLB(S) \
  uint4 eA0##S, eA1##S, eB0##S, eB1##S; \
  u32 giA##S, giB##S; \
  u32 cAe##S, cAi##S, cAo##S, cBe##S, cBi##S, cBo##S;

#define PLOAD(S, g) { \
  int pA_ = ((g) << 7) + l, pB_ = pA_ + 64; \
  const uint4* ea_ = (const uint4*)(nbr_ext + ((size_t)pA_ << 4)); \
  const uint4* eb_ = (const uint4*)(nbr_ext + ((size_t)pB_ << 4)); \
  eA0##S = ea_[0]; eA1##S = ea_[1]; \
  eB0##S = eb_[0]; eB1##S = eb_[1]; \
  giA##S = *(const u32*)(nbr_ing + 2 * pA_); \
  giB##S = *(const u32*)(nbr_ing + 2 * pB_); \
  cAe##S = cnt_ext[pA_]; cAi##S = cnt_ing[pA_]; cAo##S = cnt_ovf[pA_]; \
  cBe##S = cnt_ext[pB_]; cBi##S = cnt_ing[pB_]; cBo##S = cnt_ovf[pB_]; }

#define EXT8L(d_, v_, c_) { \
  d_ |= keep[(0u < (c_)) ? (v_.x & 0xFFFFu) : ZS]; \
  d_ |= keep[(1u < (c_)) ? (v_.x >> 16)     : ZS]; \
  d_ |= keep[(2u < (c_)) ? (v_.y & 0xFFFFu) : ZS]; \
  d_ |= keep[(3u < (c_)) ? (v_.y >> 16)     : ZS]; \
  d_ |= keep[(4u < (c_)) ? (v_.z & 0xFFFFu) : ZS]; \
  d_ |= keep[(5u < (c_)) ? (v_.z >> 16)     : ZS]; \
  d_ |= keep[(6u < (c_)) ? (v_.w & 0xFFFFu) : ZS]; \
  d_ |= keep[(7u < (c_)) ? (v_.w >> 16)     : ZS]; }

#define EXT8H(d_, v_, c_) { \
  d_ |= keep[(8u  < (c_)) ? (v_.x & 0xFFFFu) : ZS]; \
  d_ |= keep[(9u  < (c_)) ? (v_.x >> 16)     : ZS]; \
  d_ |= keep[(10u < (c_)) ? (v_.y & 0xFFFFu) : ZS]; \
  d_ |= keep[(11u < (c_)) ? (v_.y >> 16)     : ZS]; \
  d_ |= keep[(12u < (c_)) ? (v_.z & 0xFFFFu) : ZS]; \
  d_ |= keep[(13u < (c_)) ? (v_.z >> 16)     : ZS]; \
  d_ |= keep[(14u < (c_)) ? (v_.w & 0xFFFFu) : ZS]; \
  d_ |= keep[(15u < (c_)) ? (v_.w >> 16)     : ZS]; }

#define RESOLVE(S, g) { \
  const u32 gb_ = (u32)((g) << 7); \
  int pA_ = (int)gb_ + l, pB_ = pA_ + 64; \
  u32 dA_ = 0, dB_ = 0; \
  EXT8L(dA_, eA0##S, cAe##S); \
  EXT8L(dB_, eB0##S, cBe##S); \
  if (__any((int)(cAe##S > 8u))) EXT8H(dA_, eA1##S, cAe##S); \
  if (__any((int)(cBe##S > 8u))) EXT8H(dB_, eB1##S, cBe##S); \
  u64 mAA_ = 0, mBA_ = 0, mBB_ = 0; \
  if (cAi##S > 0u) mAA_ |= 1ull << ((giA##S & 0xFFFFu) - gb_); \
  if (cAi##S > 1u) mAA_ |= 1ull << ((giA##S >> 16) - gb_); \
  if (cBi##S > 0u) { u32 pos_ = (giB##S & 0xFFFFu) - gb_; \
    if (pos_ < 64u) mBA_ |= 1ull << pos_; else mBB_ |= 1ull << (pos_ - 64u); } \
  if (cBi##S > 1u) { u32 pos_ = (giB##S >> 16) - gb_; \
    if (pos_ < 64u) mBA_ |= 1ull << pos_; else mBB_ |= 1ull << (pos_ - 64u); } \
  if (cAo##S) { u32 ns_ = cAo##S < (u32)OVFC ? cAo##S : (u32)OVFC; \
    for (u32 n_ = 0; n_ < ns_; ++n_) { \
      u32 q_ = nbr_ovf[n_ * NPTS + (u32)pA_]; u32 pos_ = q_ - gb_; \
      if (pos_ < 64u) mAA_ |= 1ull << pos_; else dA_ |= keep[q_]; } } \
  if (cBo##S) { u32 ns_ = cBo##S < (u32)OVFC ? cBo##S : (u32)OVFC; \
    for (u32 n_ = 0; n_ < ns_; ++n_) { \
      u32 q_ = nbr_ovf[n_ * NPTS + (u32)pB_]; u32 pos_ = q_ - gb_; \
      if (pos_ < 64u) mBA_ |= 1ull << pos_; \
      else if (pos_ < 128u) mBB_ |= 1ull << (pos_ - 64u); \
      else dB_ |= keep[q_]; } } \
  bool aA_ = (dA_ == 0u); \
  u64 lvA_ = __ballot((int)aA_); \
  if (__any((int)(mAA_ != 0ull))) { \
    _Pragma("unroll 1") \
    for (int it_ = 0; it_ < 64; ++it_) { \
      bool nn_ = (dA_ == 0u) && ((mAA_ & lvA_) == 0ull); \
      u64 l2_ = __ballot((int)nn_); \
      aA_ = nn_; \
      if (l2_ == lvA_) break; \
      lvA_ = l2_; } } \
  bool aB_ = (dB_ == 0u) && ((mBA_ & lvA_) == 0ull); \
  u64 lvB_ = __ballot((int)aB_); \
  if (__any((int)(mBB_ != 0ull))) { \
    _Pragma("unroll 1") \
    for (int it_ = 0; it_ < 64; ++it_) { \
      bool nn_ = (dB_ == 0u) && ((mBA_ & lvA_) == 0ull) && ((mBB_ & lvB_) == 0ull); \
      u64 l2_ = __ballot((int)nn_); \
      aB_ = nn_; \
      if (l2_ == lvB_) break; \
      lvB_ = l2_; } } \
  keep[pA_] = aA_ ? (u8)1 : (u8)0; \
  keep[pB_] = aB_ ? (u8)1 : (u8)0; \
  __syncthreads(); }

__global__ __launch_bounds__(64) void k_nms(const u32* __restrict__ cnt_ext,
                                            const u32* __restrict__ cnt_ing,
                                            const u32* __restrict__ cnt_ovf,
                                            const u16* __restrict__ nbr_ext,
                                            const u16* __restrict__ nbr_ing,
                                            const u16* __restrict__ nbr_ovf,
                                            const u32* __restrict__ sorted_id,
                                            const float* __restrict__ ss,
                                            float* __restrict__ out) {
  __shared__ u8 keep[NPTS + 4];
  int l = threadIdx.x;
  if (l == 0) keep[NPTS] = 0;   // zero slot for predicated-off reads
  __syncthreads();

  DECLB(P0) DECLB(P1) DECLB(Q0) DECLB(Q1)
  PLOAD(P0, 0) PLOAD(P1, 1) PLOAD(Q0, 2) PLOAD(Q1, 3)

  for (int g = 0; g < GR; g += 4) {
    RESOLVE(P0, g)
    RESOLVE(P1, g + 1)
    if (g + 4 < GR) { PLOAD(P0, g + 4) PLOAD(P1, g + 5) }
    RESOLVE(Q0, g + 2)
    RESOLVE(Q1, g + 3)
    if (g + 6 < GR) { PLOAD(Q0, g + 6) PLOAD(Q1, g + 7) }
  }

  // epilogue: keep mask (original order) + suppressed scores (rank order)
  const uint4* sid4 = (const uint4*)sorted_id;
  const float4* ss4 = (const float4*)ss;
  for (int k4 = l; k4 < NPTS / 4; k4 += 64) {
    uint4 sid = sid4[k4];
    float4 sv = ss4[k4];
    int k = k4 << 2;
    u8 k0 = keep[k], k1 = keep[k + 1], k2 = keep[k + 2], k3 = keep[k + 3];
    out[sid.x] = k0 ? 1.0f : 0.0f;
    out[sid.y] = k1 ? 1.0f : 0.0f;
    out[sid.z] = k2 ? 1.0f : 0.0f;
    out[sid.w] = k3 ? 1.0f : 0.0f;
    float4 o;
    o.x = k0 ? sv.x : 0.0f;
    o.y = k1 ? sv.y : 0.0f;
    o.z = k2 ? sv.z : 0.0f;
    o.w = k3 ? sv.w : 0.0f;
    ((float4*)(out + NPTS))[k4] = o;
  }
}

// ---------------------------------------------------------------------------
extern "C" void kernel_launch(void* const* d_in, const int* in_sizes, int n_in,
                              void* d_out, int out_size, void* d_ws, size_t ws_size,
                              hipStream_t stream) {
  const float* coords = (const float*)d_in[0];  // [N,2]
  const float* scores = (const float*)d_in[1];  // [N]
  float* out = (float*)d_out;                   // [N keep | N suppressed scores]

  char* ws = (char*)d_ws;
  size_t off = 0;
  u16* nbr_ext   = (u16*)(ws + off); off += (size_t)EXTR * NPTS * 2;  // 256K
  u16* nbr_ing   = (u16*)(ws + off); off += (size_t)INGR * NPTS * 2;  //  32K
  u16* nbr_ovf   = (u16*)(ws + off); off += (size_t)OVFC * NPTS * 2;  // 256K
  u32* sorted_id = (u32*)(ws + off); off += (size_t)NPTS * 4;         //  32K
  float* sx      = (float*)(ws + off); off += (size_t)NPTS * 4;       //  32K
  float* sy      = (float*)(ws + off); off += (size_t)NPTS * 4;       //  32K
  float* ss      = (float*)(ws + off); off += (size_t)NPTS * 4;       //  32K
  u32* zero      = (u32*)(ws + off); off += (size_t)(3 * NPTS) * 4;   //  96K
  u32* cnt_ext = zero;
  u32* cnt_ing = zero + NPTS;
  u32* cnt_ovf = zero + 2 * NPTS;

  k_rank<<<256, 1024, 0, stream>>>(coords, scores, sorted_id, sx, sy, ss, zero);
  k_nbr<<<NTILES, 256, 0, stream>>>(sx, sy, cnt_ext, cnt_ing, cnt_ovf,
                                    nbr_ext, nbr_ing, nbr_ovf);
  k_nms<<<1, 64, 0, stream>>>(cnt_ext, cnt_ing, cnt_ovf, nbr_ext, nbr_ing,
                              nbr_ovf, sorted_id, ss, out);
}

// Round 2
// 106.803 us; speedup vs baseline: 1.3337x; 1.3337x over previous
//
#include <hip/hip_runtime.h>
#include <stdint.h>

typedef unsigned int u32;
typedef unsigned long long u64;
typedef unsigned short u16;
typedef unsigned char u8;

#define NPTS 8192
#define NTILES (32 * 33)

#define CAP 12           // row-major earlier-neighbor slots per point
#define OVFC 16          // overflow slots per point (exactness tail)
#define ZS NPTS          // neutral LDS slot, holds state==2 (SUPP)

// ---------------------------------------------------------------------------
// A: rank by counting, register-tiled 4 points/thread (unchanged core).
// Block 0 zeroes cnt | cnt_ovf (2*NPTS u32).
// ---------------------------------------------------------------------------
__global__ __launch_bounds__(1024) void k_rank(const float* __restrict__ coords,
                                               const float* __restrict__ scores,
                                               u32* __restrict__ sorted_id,
                                               float* __restrict__ sx,
                                               float* __restrict__ sy,
                                               float* __restrict__ ss,
                                               u32* __restrict__ zero_region) {
  __shared__ u32 skey[NPTS];
  __shared__ u32 part[16][4];
  int t = threadIdx.x, B = blockIdx.x;
  for (int k = t; k < NPTS; k += 1024) skey[k] = __float_as_uint(scores[k]);
  if (B == 0) {
    for (int k = t; k < 2 * NPTS; k += 1024) zero_region[k] = 0;
  }
  __syncthreads();

  int qd = t >> 7;        // quad 0..7 (4 points each)
  int s = t & 127;        // slice 0..127 (64 keys each)
  int p0 = B * 32 + qd * 4;
  int sp = B >> 1;        // the one slice containing this block's points
  u32 kp0 = skey[p0], kp1 = skey[p0 + 1], kp2 = skey[p0 + 2], kp3 = skey[p0 + 3];
  u32 c0 = 0, c1 = 0, c2 = 0, c3 = 0;
  const uint4* k4 = (const uint4*)skey;

  if (s != sp) {
    bool below = (s < sp);
    u32 a0 = below ? kp0 - 1u : kp0;  // >= via > (kp-1); kp==0 fixed below
    u32 a1 = below ? kp1 - 1u : kp1;
    u32 a2 = below ? kp2 - 1u : kp2;
    u32 a3 = below ? kp3 - 1u : kp3;
    int b4 = s << 4;
#pragma unroll 4
    for (int j = 0; j < 16; ++j) {
      int jj = (j + s) & 15;          // rotate across bank groups
      uint4 kv = k4[b4 + jj];
      c0 += (kv.x > a0) + (kv.y > a0) + (kv.z > a0) + (kv.w > a0);
      c1 += (kv.x > a1) + (kv.y > a1) + (kv.z > a1) + (kv.w > a1);
      c2 += (kv.x > a2) + (kv.y > a2) + (kv.z > a2) + (kv.w > a2);
      c3 += (kv.x > a3) + (kv.y > a3) + (kv.z > a3) + (kv.w > a3);
    }
    if (below) {  // underflow fixup: kp==0 means all 64 keys count as >=
      if (kp0 == 0) c0 += 64;
      if (kp1 == 0) c1 += 64;
      if (kp2 == 0) c2 += 64;
      if (kp3 == 0) c3 += 64;
    }
  } else {
    int q0 = s << 6;
    int mo = p0 - q0;  // 0..60, multiple of 4
    u32 a0 = kp0 - 1u, a1 = kp1 - 1u, a2 = kp2 - 1u, a3 = kp3 - 1u;
    for (int j = 0; j < mo; ++j) {       // q < p0: count >=
      u32 kq = skey[q0 + j];
      c0 += (kq > a0); c1 += (kq > a1); c2 += (kq > a2); c3 += (kq > a3);
    }
    if (kp0 == 0) c0 += mo;
    if (kp1 == 0) c1 += mo;
    if (kp2 == 0) c2 += mo;
    if (kp3 == 0) c3 += mo;
#pragma unroll
    for (int j2 = 0; j2 < 4; ++j2) {     // q in [p0, p0+4): exact tie logic
      int q = p0 + j2;
      u32 kq = skey[q];
      c0 += (kq > kp0) || (kq == kp0 && q < p0);
      c1 += (kq > kp1) || (kq == kp1 && q < p0 + 1);
      c2 += (kq > kp2) || (kq == kp2 && q < p0 + 2);
      c3 += (kq > kp3) || (kq == kp3 && q < p0 + 3);
    }
    for (int j = mo + 4; j < 64; ++j) {  // q > p_e: count >
      u32 kq = skey[q0 + j];
      c0 += (kq > kp0); c1 += (kq > kp1); c2 += (kq > kp2); c3 += (kq > kp3);
    }
  }

#pragma unroll
  for (int d = 1; d < 64; d <<= 1) {
    c0 += __shfl_xor(c0, d);
    c1 += __shfl_xor(c1, d);
    c2 += __shfl_xor(c2, d);
    c3 += __shfl_xor(c3, d);
  }
  int w = t >> 6;
  if ((t & 63) == 0) { part[w][0] = c0; part[w][1] = c1; part[w][2] = c2; part[w][3] = c3; }
  __syncthreads();
  if (t < 32) {
    int qd2 = t >> 2, e = t & 3;
    u32 r = part[qd2 * 2][e] + part[qd2 * 2 + 1][e];
    int p = B * 32 + t;
    sorted_id[r] = (u32)p;
    sx[r] = coords[2 * p];      // bitwise copies keep arithmetic exact
    sy[r] = coords[2 * p + 1];
    ss[r] = scores[p];
  }
}

// ---------------------------------------------------------------------------
// B: neighbor lists (triangular-tile lineage). Unified row-major per-point
// list (CAP slots) + shared overflow (exactness up to CAP+OVFC=28 earlier
// nbrs; P(exceed) ~ 1e-11 at lambda<=6.3). d2<64 <=> sqrt(d2)<8 exactly in
// f32. Distance arithmetic unchanged.
// ---------------------------------------------------------------------------
__global__ __launch_bounds__(256) void k_nbr(const float* __restrict__ sx,
                                             const float* __restrict__ sy,
                                             u32* __restrict__ cnt,
                                             u32* __restrict__ cnt_ovf,
                                             u16* __restrict__ nbr,
                                             u16* __restrict__ nbr_ovf) {
  __shared__ float qx[128], qy[128];
  int b = blockIdx.x;
  int R = (int)((__fsqrt_rn(4.0f * (float)b + 1.0f) - 1.0f) * 0.5f);
  while ((R + 1) * (R + 2) <= b) ++R;
  while (R * (R + 1) > b) --R;
  int C = b - R * (R + 1);
  int t = threadIdx.x;
  int q0 = C << 7;
  int r = (R << 8) + t;
  if (t < 128) qx[t] = sx[q0 + t];
  else         qy[t - 128] = sy[q0 + t - 128];
  __syncthreads();

  float x = sx[r], y = sy[r];
  int jlim = 128;
  int dC = C - 2 * R;
  if (dC >= 0) {
    jlim = t - (dC << 7);
    if (jlim < 0) jlim = 0;
    if (jlim > 128) jlim = 128;
  }
  const float4* x4 = (const float4*)qx;
  const float4* y4 = (const float4*)qy;
  for (int jg = 0; jg < 4; ++jg) {
    int base = jg << 5;
    int v = jlim - base;
    u32 gm = (v >= 32) ? 0xFFFFFFFFu : ((v <= 0) ? 0u : ((1u << v) - 1u));
    u32 m = 0;
#pragma unroll
    for (int j4 = 0; j4 < 8; ++j4) {
      float4 xv = x4[(base >> 2) + j4];
      float4 yv = y4[(base >> 2) + j4];
      // mirror reference arithmetic: sub, mul, mul, add (no fma contraction)
      float dx0 = __fsub_rn(x, xv.x), dy0 = __fsub_rn(y, yv.x);
      float dx1 = __fsub_rn(x, xv.y), dy1 = __fsub_rn(y, yv.y);
      float dx2 = __fsub_rn(x, xv.z), dy2 = __fsub_rn(y, yv.z);
      float dx3 = __fsub_rn(x, xv.w), dy3 = __fsub_rn(y, yv.w);
      if (__fadd_rn(__fmul_rn(dx0, dx0), __fmul_rn(dy0, dy0)) < 64.0f) m |= 1u << (4 * j4 + 0);
      if (__fadd_rn(__fmul_rn(dx1, dx1), __fmul_rn(dy1, dy1)) < 64.0f) m |= 1u << (4 * j4 + 1);
      if (__fadd_rn(__fmul_rn(dx2, dx2), __fmul_rn(dy2, dy2)) < 64.0f) m |= 1u << (4 * j4 + 2);
      if (__fadd_rn(__fmul_rn(dx3, dx3), __fmul_rn(dy3, dy3)) < 64.0f) m |= 1u << (4 * j4 + 3);
    }
    m &= gm;
    while (m) {  // rare: lambda ~3 hits/point average
      int j2 = __builtin_ctz(m);
      m &= m - 1;
      int q = q0 + base + j2;   // strictly q < r (lower triangle)
      u32 sl = atomicAdd(&cnt[r], 1u);
      if (sl < CAP) nbr[(size_t)r * CAP + sl] = (u16)q;
      else {
        u32 so = atomicAdd(&cnt_ovf[r], 1u);
        if (so < OVFC) nbr_ovf[so * NPTS + r] = (u16)q;
      }
    }
  }
}

// ---------------------------------------------------------------------------
// C: monotone 3-state frontier fixpoint over ALL points at once.
// state: 0=undecided, 1=keep(final), 2=supp(final). Rules:
//   supp as soon as ANY earlier nbr is keep;
//   keep when ALL earlier nbrs are supp.
// States only advance undecided->final, so chaotic (Gauss-Seidel) reads
// within a round are always correct; rounds = decision-DAG depth
// (~O(log N) for random ranks), NOT segment-sequential. Min-rank undecided
// point is always decidable => guaranteed progress => "no change in a full
// round" <=> all decided (exact greedy fixpoint). 1024 thr x 8 pts,
// 16 waves for TLP, one barrier/round (rotating 4-slot changed flag).
// Neighbor addresses predicated ONCE at prefetch: slots>=cnt point at a
// neutral LDS slot holding 2, so the round body is pure ds_read_u8+or+and:
//   orv&1  <=> some nbr kept   (suppress now)
//   andv&2 <=> all nbrs supp   (keep now)
// ---------------------------------------------------------------------------
__global__ __launch_bounds__(1024) void k_nms(const u32* __restrict__ cnt,
                                              const u32* __restrict__ cnt_ovf,
                                              const u16* __restrict__ nbr,
                                              const u16* __restrict__ nbr_ovf,
                                              const u32* __restrict__ sorted_id,
                                              const float* __restrict__ ss,
                                              float* __restrict__ out) {
  __shared__ u8 state[NPTS + 4];
  __shared__ int flag[4];
  int t = threadIdx.x;

  // issue neighbor-row prefetch first (VMEM latency hides under LDS init)
  uint2 row[8][3];
  u32 cn[8], co[8];
#pragma unroll
  for (int k = 0; k < 8; ++k) {
    int p = t + (k << 10);
    const uint2* rp = (const uint2*)(nbr + (size_t)p * CAP);  // 24B rows, 8-aligned
    row[k][0] = rp[0]; row[k][1] = rp[1]; row[k][2] = rp[2];
    cn[k] = cnt[p]; co[k] = cnt_ovf[p];
  }

  ((u32*)state)[t] = 0;
  ((u32*)state)[1024 + t] = 0;
  if (t == 0) state[NPTS] = 2;   // neutral slot: reads as SUPP
  if (t < 4) flag[t] = 0;
  __syncthreads();               // zeros visible before seeding writes

  int adr[8][CAP];
  u32 live = 0;
#pragma unroll
  for (int k = 0; k < 8; ++k) {
    int p = t + (k << 10);
    u32 c = cn[k] < (u32)CAP ? cn[k] : (u32)CAP;
    u32 h0 = row[k][0].x, h1 = row[k][0].y, h2 = row[k][1].x;
    u32 h3 = row[k][1].y, h4 = row[k][2].x, h5 = row[k][2].y;
    u32 hv[6] = {h0, h1, h2, h3, h4, h5};
#pragma unroll
    for (int n = 0; n < CAP; ++n) {  // static indices -> registers
      u32 v = (n & 1) ? (hv[n >> 1] >> 16) : (hv[n >> 1] & 0xFFFFu);
      adr[k][n] = ((u32)n < c) ? (int)v : (int)ZS;
    }
    if (c == 0 && co[k] == 0) state[p] = 1;  // no earlier nbrs: kept now
    else live |= 1u << k;
  }
  __syncthreads();               // seeds visible before round 1

  for (int r = 1; r <= NPTS; ++r) {
    if (t == 0) flag[(r + 2) & 3] = 0;
    bool changed = false;
#pragma unroll
    for (int k = 0; k < 8; ++k) {
      if (live & (1u << k)) {
        int p = t + (k << 10);
        u32 s0 = state[adr[k][0]], s1 = state[adr[k][1]];
        u32 s2 = state[adr[k][2]], s3 = state[adr[k][3]];
        u32 orv = s0 | s1 | s2 | s3;
        u32 andv = s0 & s1 & s2 & s3;
        if (adr[k][4] != (int)ZS) {       // cnt > 4 (lane-predicated)
          u32 a0 = state[adr[k][4]], a1 = state[adr[k][5]];
          u32 a2 = state[adr[k][6]], a3 = state[adr[k][7]];
          orv |= a0 | a1 | a2 | a3;
          andv &= a0 & a1 & a2 & a3;
        }
        if (adr[k][8] != (int)ZS) {       // cnt > 8
          u32 b0 = state[adr[k][8]], b1 = state[adr[k][9]];
          u32 b2 = state[adr[k][10]], b3 = state[adr[k][11]];
          orv |= b0 | b1 | b2 | b3;
          andv &= b0 & b1 & b2 & b3;
        }
        if (co[k]) {                      // ultra-rare overflow tail
          u32 no = co[k] < (u32)OVFC ? co[k] : (u32)OVFC;
          for (u32 n = 0; n < no; ++n) {
            u32 q = nbr_ovf[n * NPTS + (u32)p];
            u32 s = state[q];
            orv |= s; andv &= s;
          }
        }
        if (orv & 1u)       { state[p] = 2; live &= ~(1u << k); changed = true; }
        else if (andv & 2u) { state[p] = 1; live &= ~(1u << k); changed = true; }
      }
    }
    if (changed) flag[r & 3] = 1;
    __syncthreads();
    if (flag[r & 3] == 0) break;  // full round w/o change <=> all decided
  }

  // epilogue: keep mask (original order) + suppressed scores (rank order)
  const uint4* sid4 = (const uint4*)sorted_id;
  const float4* ss4 = (const float4*)ss;
  for (int k4 = t; k4 < NPTS / 4; k4 += 1024) {
    uint4 sid = sid4[k4];
    float4 sv = ss4[k4];
    int k = k4 << 2;
    bool k0 = (state[k] == 1), k1 = (state[k + 1] == 1);
    bool k2 = (state[k + 2] == 1), k3 = (state[k + 3] == 1);
    out[sid.x] = k0 ? 1.0f : 0.0f;
    out[sid.y] = k1 ? 1.0f : 0.0f;
    out[sid.z] = k2 ? 1.0f : 0.0f;
    out[sid.w] = k3 ? 1.0f : 0.0f;
    float4 o;
    o.x = k0 ? sv.x : 0.0f;
    o.y = k1 ? sv.y : 0.0f;
    o.z = k2 ? sv.z : 0.0f;
    o.w = k3 ? sv.w : 0.0f;
    ((float4*)(out + NPTS))[k4] = o;
  }
}

// ---------------------------------------------------------------------------
extern "C" void kernel_launch(void* const* d_in, const int* in_sizes, int n_in,
                              void* d_out, int out_size, void* d_ws, size_t ws_size,
                              hipStream_t stream) {
  const float* coords = (const float*)d_in[0];  // [N,2]
  const float* scores = (const float*)d_in[1];  // [N]
  float* out = (float*)d_out;                   // [N keep | N suppressed scores]

  char* ws = (char*)d_ws;
  size_t off = 0;
  u16* nbr       = (u16*)(ws + off); off += (size_t)CAP * NPTS * 2;   // 192K
  u16* nbr_ovf   = (u16*)(ws + off); off += (size_t)OVFC * NPTS * 2;  // 256K
  u32* sorted_id = (u32*)(ws + off); off += (size_t)NPTS * 4;         //  32K
  float* sx      = (float*)(ws + off); off += (size_t)NPTS * 4;       //  32K
  float* sy      = (float*)(ws + off); off += (size_t)NPTS * 4;       //  32K
  float* ss      = (float*)(ws + off); off += (size_t)NPTS * 4;       //  32K
  u32* zero      = (u32*)(ws + off); off += (size_t)(2 * NPTS) * 4;   //  64K
  u32* cnt     = zero;
  u32* cnt_ovf = zero + NPTS;

  k_rank<<<256, 1024, 0, stream>>>(coords, scores, sorted_id, sx, sy, ss, zero);
  k_nbr<<<NTILES, 256, 0, stream>>>(sx, sy, cnt, cnt_ovf, nbr, nbr_ovf);
  k_nms<<<1, 1024, 0, stream>>>(cnt, cnt_ovf, nbr, nbr_ovf, sorted_id, ss, out);
}